// Round 10
// baseline (163.684 us; speedup 1.0000x reference)
//
#include <hip/hip_runtime.h>
#include <stdint.h>

#define N_NODES 100000
#define F_DIM   500
#define C_DIM   40
#define H_DIM   256
#define HX_DIM  64
#define O_DIM   320   // H + HX
#define E_NUM   1600000

typedef unsigned short u16;
typedef unsigned int   u32;
typedef __attribute__((ext_vector_type(4))) u16    u16x4;
typedef __attribute__((ext_vector_type(8))) u16    u16x8;
typedef __attribute__((ext_vector_type(4))) float  f32x4;
typedef __attribute__((ext_vector_type(8))) short  bf16x8;  // MFMA A/B frag

__device__ __forceinline__ float bf2f(u16 v) {
  u32 u = ((u32)v) << 16;
  return __builtin_bit_cast(float, u);
}
__device__ __forceinline__ u16 f2bf(float f) {   // round-to-nearest-even
  u32 x = __builtin_bit_cast(u32, f);
  x += 0x7fffu + ((x >> 16) & 1u);
  return (u16)(x >> 16);
}

// ---------------- Kernel 0: train_mask encoding detector ----------------
__global__ __launch_bounds__(256) void k_detect(const u32* __restrict__ tm, int* __restrict__ flag)
{
  __shared__ int s;
  if (threadIdx.x == 0) s = 0;
  __syncthreads();
  int local = 0;
  #pragma unroll
  for (int j = 0; j < 16; ++j) {
    if (tm[j * 256 + threadIdx.x] > 1u) local = 1;
  }
  if (local) s = 1;
  __syncthreads();
  if (threadIdx.x == 0) *flag = s;
}

// ---------------- Kernel 0b: pre-convert W=[fc1_w;xenc_w] to bf16, K-chunked ----------------
// wws[c*10240 + r*32 + s*8 + j] = bf16(W[r][c*32+s*8+j]), ZERO-PADDED past K=500
// (the zero pad is what makes the A-side K-tail garbage harmless in k_fused).
__global__ __launch_bounds__(256) void k_cvtw(
    const float* __restrict__ fc1w, const float* __restrict__ xencw, u16* __restrict__ wws)
{
  const int g = blockIdx.x * 256 + threadIdx.x;   // 20480 groups
  const int c = g / 1280;
  const int rem = g - c * 1280;
  const int r = rem >> 2;
  const int k0 = c * 32 + (rem & 3) * 8;
  const float* src = (r < H_DIM) ? (fc1w + (long)r * F_DIM)
                                 : (xencw + (long)(r - H_DIM) * F_DIM);
  f32x4 v0 = {0.f, 0.f, 0.f, 0.f}, v1 = v0;
  if (k0 + 4 <= F_DIM) v0 = *(const f32x4*)(src + k0);
  if (k0 + 8 <= F_DIM) v1 = *(const f32x4*)(src + k0 + 4);
  u16x8 o;
  #pragma unroll
  for (int i = 0; i < 4; ++i) { o[i] = f2bf(v0[i]); o[4 + i] = f2bf(v1[i]); }
  *(u16x8*)(wws + (size_t)g * 8) = o;
}

// ---------------- Kernel 1: FUSED, barrier-free phase 1 ----------------
// Phase 1: per-wave independent K-loop. A-frags load DIRECTLY from x (f32->cvt->MFMA,
//   lane-exact frag addressing; 4 col-waves share rows via L1). B-frags direct from wws
//   (contiguous 1KB wave reads, L2). NO LDS, NO barriers in phase 1.
// K-tail: k clamped to <=496; wws zero-pad kills garbage products. Rows clamped to N-1.
// Phase 2: h|xe -> LDS (stride 328) -> validated rowhead MFMA + softmax + s_q/s_k.
#define G_BM 64
#define G_BK 32
#define BN   320
#define RH_LD 328

__global__ __launch_bounds__(512, 4) void k_fused(
    const float* __restrict__ x, const u16* __restrict__ wws,
    const float* __restrict__ fc1b, const float* __restrict__ xencb,
    const int* __restrict__ y, const void* __restrict__ tmask,
    const float* __restrict__ fc2w, const float* __restrict__ fc2b,
    const float* __restrict__ pw, const int* __restrict__ mask_flag,
    float* __restrict__ out_lp, float* __restrict__ sq_out, float* __restrict__ sk_out)
{
  __shared__ __align__(16) u16 smem[36736];   // 73472 B, phase-2 only
  u16* sOut = smem;            // [64][328]
  u16* sBp  = smem + 20992;    // [48][328]

  const int tid  = threadIdx.x;
  const int lane = tid & 63;
  const int wid  = tid >> 6;
  const int wr   = wid >> 2;                // row half (0..1)
  const int wcol = wid & 3;                 // col strip (0..3)
  const int l15 = lane & 15, lgrp = lane >> 4;
  const long rowbase = (long)blockIdx.x * G_BM;

  // per-lane A row pointers, clamped (invalid rows compute garbage, never stored)
  long r0 = rowbase + wr * 32 + l15;
  long r1 = r0 + 16;
  if (r0 > N_NODES - 1) r0 = N_NODES - 1;
  if (r1 > N_NODES - 1) r1 = N_NODES - 1;
  const float* ap0 = x + r0 * F_DIM;
  const float* ap1 = x + r1 * F_DIM;

  // B fragment base (validated r7-r9 layout: contiguous 1KB per wave-frag)
  const u16* bbase = wws + (wcol * 80 + l15) * 32 + lgrp * 8;

  f32x4 acc[2][5];
  #pragma unroll
  for (int m = 0; m < 2; ++m)
    #pragma unroll
    for (int n = 0; n < 5; ++n)
      acc[m][n] = (f32x4){0.f, 0.f, 0.f, 0.f};

  f32x4 a0l, a0h, a1l, a1h;     // A(kc) f32 in flight
  bf16x8 bP[5], bQ[5];          // B double buffer

#define LA(kc)                                                                 \
  {                                                                            \
    const int k0 = (kc) * G_BK + lgrp * 8;                                     \
    const int ka = (k0     > 496) ? 496 : k0;                                  \
    const int kb = (k0 + 4 > 496) ? 496 : (k0 + 4);                            \
    a0l = *(const f32x4*)(ap0 + ka);  a0h = *(const f32x4*)(ap0 + kb);         \
    a1l = *(const f32x4*)(ap1 + ka);  a1h = *(const f32x4*)(ap1 + kb);         \
  }

#define LB(dst, kc)                                                            \
  {                                                                            \
    const u16* bp = bbase + (size_t)(kc) * (BN * G_BK);                        \
    _Pragma("unroll")                                                          \
    for (int n = 0; n < 5; ++n) dst[n] = *(const bf16x8*)(bp + n * 512);       \
  }

#define GS(kc, BU, BL)                                                         \
  {                                                                            \
    bf16x8 af0, af1;                                                           \
    _Pragma("unroll")                                                          \
    for (int i = 0; i < 4; ++i) {                                              \
      af0[i]     = (short)f2bf(a0l[i]);  af0[4 + i] = (short)f2bf(a0h[i]);     \
      af1[i]     = (short)f2bf(a1l[i]);  af1[4 + i] = (short)f2bf(a1h[i]);     \
    }                                                                          \
    if ((kc) < 15) { LA((kc) + 1); LB(BL, (kc) + 1); }                         \
    _Pragma("unroll")                                                          \
    for (int n = 0; n < 5; ++n) {                                              \
      acc[0][n] = __builtin_amdgcn_mfma_f32_16x16x32_bf16(af0, BU[n], acc[0][n], 0, 0, 0); \
      acc[1][n] = __builtin_amdgcn_mfma_f32_16x16x32_bf16(af1, BU[n], acc[1][n], 0, 0, 0); \
    }                                                                          \
  }

  LA(0); LB(bP, 0);
  GS(0,  bP, bQ)  GS(1,  bQ, bP)  GS(2,  bP, bQ)  GS(3,  bQ, bP)
  GS(4,  bP, bQ)  GS(5,  bQ, bP)  GS(6,  bP, bQ)  GS(7,  bQ, bP)
  GS(8,  bP, bQ)  GS(9,  bQ, bP)  GS(10, bP, bQ)  GS(11, bQ, bP)
  GS(12, bP, bQ)  GS(13, bQ, bP)  GS(14, bP, bQ)  GS(15, bQ, bP)

  // ---- phase 2: h|xe tile -> LDS (validated layout) + B' stage, ONE barrier ----
  #pragma unroll
  for (int n = 0; n < 5; ++n) {
    const int col = wcol * 80 + n * 16 + l15;
    const float bias = (col < H_DIM) ? fc1b[col] : xencb[col - H_DIM];
    #pragma unroll
    for (int m = 0; m < 2; ++m) {
      const int rr0 = wr * 32 + m * 16 + lgrp * 4;
      #pragma unroll
      for (int rg = 0; rg < 4; ++rg)
        sOut[(rr0 + rg) * RH_LD + col] = f2bf(fmaxf(acc[m][n][rg] + bias, 0.f));
    }
  }
  // B' rows 0-39 [fc2w | 0], 40 [0|w_xq], 41 [0|w_xk], 42-47 zero (48 x 40 groups)
  #pragma unroll
  for (int it = 0; it < 4; ++it) {
    const int g = it * 512 + tid;
    if (g < 1920) {
      const int r = g / 40, c = g - r * 40;
      const int k0 = c * 8;
      u16x8 v = {0, 0, 0, 0, 0, 0, 0, 0};
      const float* src = nullptr;
      if (r < C_DIM) { if (k0 < H_DIM) src = fc2w + r * H_DIM + k0; }
      else if (r == C_DIM)     { if (k0 >= H_DIM) src = pw + (k0 - H_DIM); }
      else if (r == C_DIM + 1) { if (k0 >= H_DIM) src = pw + HX_DIM + (k0 - H_DIM); }
      if (src) {
        const f32x4 v0 = *(const f32x4*)src;
        const f32x4 v1 = *(const f32x4*)(src + 4);
        #pragma unroll
        for (int i = 0; i < 4; ++i) { v[i] = f2bf(v0[i]); v[4 + i] = f2bf(v1[i]); }
      }
      *(u16x8*)&sBp[r * RH_LD + c * 8] = v;
    }
  }
  __syncthreads();

  // ---- rowhead (waves 0-3; 16 rows each) — validated round-4/9 math ----
  if (wid < 4) {
    f32x4 racc[3];
    #pragma unroll
    for (int n = 0; n < 3; ++n) racc[n] = (f32x4){0.f, 0.f, 0.f, 0.f};
    const u16* pa = &sOut[(wid * 16 + l15) * RH_LD + lgrp * 8];
    const u16* pb = &sBp[l15 * RH_LD + lgrp * 8];
    #pragma unroll
    for (int kc = 0; kc < 10; ++kc) {
      const bf16x8 a = *(const bf16x8*)(pa + kc * 32);
      #pragma unroll
      for (int n = 0; n < 3; ++n) {
        const bf16x8 b = *(const bf16x8*)(pb + n * 16 * RH_LD + kc * 32);
        racc[n] = __builtin_amdgcn_mfma_f32_16x16x32_bf16(a, b, racc[n], 0, 0, 0);
      }
    }

    const int c0 = l15, c1 = 16 + l15, c2 = 32 + l15;
    const bool v2 = (l15 < 8);
    const float b0 = fc2b[c0], b1 = fc2b[c1], b2 = v2 ? fc2b[c2] : 0.f;
    const float wq0 = pw[2 * HX_DIM + c0], wq1 = pw[2 * HX_DIM + c1],
                wq2 = v2 ? pw[2 * HX_DIM + c2] : 0.f;
    const float wk0 = pw[2 * HX_DIM + C_DIM + c0], wk1 = pw[2 * HX_DIM + C_DIM + c1],
                wk2 = v2 ? pw[2 * HX_DIM + C_DIM + c2] : 0.f;
    const bool byte_mask = (*mask_flag != 0);

    #pragma unroll
    for (int rg = 0; rg < 4; ++rg) {
      const long row = rowbase + wid * 16 + lgrp * 4 + rg;
      const bool rv = (row < N_NODES);
      const long rowc = rv ? row : (N_NODES - 1);
      const float lg0 = racc[0][rg] + b0;
      const float lg1 = racc[1][rg] + b1;
      const float lg2 = racc[2][rg] + b2;
      const float sxq = __shfl(racc[2][rg], (lane & 48) | 8, 64);   // col 40: xe.w_xq
      const float sxk = __shfl(racc[2][rg], (lane & 48) | 9, 64);   // col 41: xe.w_xk

      float m = fmaxf(lg0, lg1);
      if (v2) m = fmaxf(m, lg2);
      #pragma unroll
      for (int off = 1; off < 16; off <<= 1) m = fmaxf(m, __shfl_xor(m, off, 64));
      const float e0 = __expf(lg0 - m), e1 = __expf(lg1 - m),
                  e2 = v2 ? __expf(lg2 - m) : 0.f;
      float s = e0 + e1 + e2;
      #pragma unroll
      for (int off = 1; off < 16; off <<= 1) s += __shfl_xor(s, off, 64);
      const float lse = m + __logf(s);
      const float inv = 1.f / s;

      const int yv = y[rowc];
      const bool tm = byte_mask ? (((const unsigned char*)tmask)[rowc] != 0)
                                : (((const int*)tmask)[rowc] != 0);
      const float p0 = tm ? (c0 == yv ? 1.f : 0.f) : e0 * inv;
      const float p1 = tm ? (c1 == yv ? 1.f : 0.f) : e1 * inv;
      const float p2 = tm ? (c2 == yv ? 1.f : 0.f) : e2 * inv;
      float sq = p0 * wq0 + p1 * wq1 + p2 * wq2;
      float sk = p0 * wk0 + p1 * wk1 + p2 * wk2;
      #pragma unroll
      for (int off = 1; off < 16; off <<= 1) {
        sq += __shfl_xor(sq, off, 64);
        sk += __shfl_xor(sk, off, 64);
      }

      if (rv) {
        float* lp = out_lp + row * C_DIM;
        lp[c0] = lg0 - lse;
        lp[c1] = lg1 - lse;
        if (v2) lp[c2] = lg2 - lse;
        if (l15 == 0) { sq_out[row] = sq + sxq; sk_out[row] = sk + sxk; }
      }
    }
  }
#undef LA
#undef LB
#undef GS
}

// ---------------- Kernel 3: edge scores ----------------
__global__ __launch_bounds__(256) void k_edges(
    const int* __restrict__ ei, const int* __restrict__ ein,
    const float* __restrict__ sq, const float* __restrict__ sk,
    const float* __restrict__ pb, float* __restrict__ out)
{
  const int e = blockIdx.x * 256 + threadIdx.x;
  if (e >= E_NUM) return;
  const float b = pb[0];
  const int a0 = ei[e],  a1 = ei[E_NUM + e];
  out[e] = sq[a0] + sk[a1] + b;
  const int c0 = ein[e], c1 = ein[E_NUM + e];
  out[E_NUM + e] = sq[c0] + sk[c1] + b;
}

extern "C" void kernel_launch(void* const* d_in, const int* in_sizes, int n_in,
                              void* d_out, int out_size, void* d_ws, size_t ws_size,
                              hipStream_t stream)
{
  const float* x     = (const float*)d_in[0];
  const int*   y     = (const int*)d_in[1];
  const void*  tm    = d_in[2];
  const int*   ei    = (const int*)d_in[3];
  const int*   ein   = (const int*)d_in[4];
  const float* fc1w  = (const float*)d_in[5];
  const float* fc1b  = (const float*)d_in[6];
  const float* fc2w  = (const float*)d_in[7];
  const float* fc2b  = (const float*)d_in[8];
  const float* xencw = (const float*)d_in[9];
  const float* xencb = (const float*)d_in[10];
  const float* pw    = (const float*)d_in[11];
  const float* pb    = (const float*)d_in[12];
  float* out = (float*)d_out;

  // ws: | s_q | s_k | flag | wws (320 KB)   (region below 64 MB unused now)
  float* sq   = (float*)((char*)d_ws + (size_t)N_NODES * O_DIM * 2);
  float* sk   = sq + N_NODES;
  int*   flag = (int*)(sk + N_NODES);
  u16*   wws  = (u16*)((char*)d_ws + 64800064);

  k_detect<<<1, 256, 0, stream>>>((const u32*)tm, flag);
  k_cvtw  <<<80, 256, 0, stream>>>(fc1w, xencw, wws);
  const int nrb = (N_NODES + G_BM - 1) / G_BM;    // 1563
  k_fused <<<nrb, 512, 0, stream>>>(x, wws, fc1b, xencb, y, tm, fc2w, fc2b, pw, flag,
                                    out + 2 * (size_t)E_NUM, sq, sk);
  k_edges <<<E_NUM / 256, 256, 0, stream>>>(ei, ein, sq, sk, pb, out);
}

// Round 11
// 153.725 us; speedup vs baseline: 1.0648x; 1.0648x over previous
//
#include <hip/hip_runtime.h>
#include <stdint.h>

#define N_NODES 100000
#define F_DIM   500
#define C_DIM   40
#define H_DIM   256
#define HX_DIM  64
#define O_DIM   320   // H + HX
#define E_NUM   1600000

typedef unsigned short u16;
typedef unsigned int   u32;
typedef __attribute__((ext_vector_type(4))) u16    u16x4;
typedef __attribute__((ext_vector_type(8))) u16    u16x8;
typedef __attribute__((ext_vector_type(4))) float  f32x4;
typedef __attribute__((ext_vector_type(8))) short  bf16x8;  // MFMA A/B frag

__device__ __forceinline__ float bf2f(u16 v) {
  u32 u = ((u32)v) << 16;
  return __builtin_bit_cast(float, u);
}
__device__ __forceinline__ u16 f2bf(float f) {   // round-to-nearest-even
  u32 x = __builtin_bit_cast(u32, f);
  x += 0x7fffu + ((x >> 16) & 1u);
  return (u16)(x >> 16);
}

// ---------------- Kernel 0: train_mask encoding detector ----------------
__global__ __launch_bounds__(256) void k_detect(const u32* __restrict__ tm, int* __restrict__ flag)
{
  __shared__ int s;
  if (threadIdx.x == 0) s = 0;
  __syncthreads();
  int local = 0;
  #pragma unroll
  for (int j = 0; j < 16; ++j) {
    if (tm[j * 256 + threadIdx.x] > 1u) local = 1;
  }
  if (local) s = 1;
  __syncthreads();
  if (threadIdx.x == 0) *flag = s;
}

// ---------------- Kernel 0b: W=[fc1_w;xenc_w] -> bf16, K-chunked frag layout ----------------
// wws[c*10240 + r*32 + s*8 + j] = bf16(W[r][c*32+s*8+j]), zero-padded past K=500.
__global__ __launch_bounds__(256) void k_cvtw(
    const float* __restrict__ fc1w, const float* __restrict__ xencw, u16* __restrict__ wws)
{
  const int g = blockIdx.x * 256 + threadIdx.x;   // 20480 groups
  const int c = g / 1280;
  const int rem = g - c * 1280;
  const int r = rem >> 2;
  const int k0 = c * 32 + (rem & 3) * 8;
  const float* src = (r < H_DIM) ? (fc1w + (long)r * F_DIM)
                                 : (xencw + (long)(r - H_DIM) * F_DIM);
  f32x4 v0 = {0.f, 0.f, 0.f, 0.f}, v1 = v0;
  if (k0 + 4 <= F_DIM) v0 = *(const f32x4*)(src + k0);
  if (k0 + 8 <= F_DIM) v1 = *(const f32x4*)(src + k0 + 4);
  u16x8 o;
  #pragma unroll
  for (int i = 0; i < 4; ++i) { o[i] = f2bf(v0[i]); o[4 + i] = f2bf(v1[i]); }
  *(u16x8*)(wws + (size_t)g * 8) = o;
}

// ---------------- Kernel 0c: B' (48 x 320) -> bf16 K-chunked frag layout ----------------
// B' rows: 0-39 [fc2w | 0], 40 [0 | w_xq], 41 [0 | w_xk], 42-47 zero.
// wwsB[kc*1536 + r*32 + s*8 + j], kc = 0..9 over K=320.
__global__ __launch_bounds__(256) void k_cvtw2(
    const float* __restrict__ fc2w, const float* __restrict__ pw, u16* __restrict__ wwsB)
{
  const int g = blockIdx.x * 256 + threadIdx.x;   // 1920 groups
  if (g >= 1920) return;
  const int kc = g / 192;
  const int rem = g - kc * 192;
  const int r = rem >> 2;
  const int k0 = kc * 32 + (rem & 3) * 8;
  const float* src = nullptr;
  if (r < C_DIM)           { if (k0 + 8 <= H_DIM) src = fc2w + r * H_DIM + k0; }
  else if (r == C_DIM)     { if (k0 >= H_DIM) src = pw + (k0 - H_DIM); }
  else if (r == C_DIM + 1) { if (k0 >= H_DIM) src = pw + HX_DIM + (k0 - H_DIM); }
  u16x8 o = {0, 0, 0, 0, 0, 0, 0, 0};
  if (src) {
    const f32x4 v0 = *(const f32x4*)src;
    const f32x4 v1 = *(const f32x4*)(src + 4);
    #pragma unroll
    for (int i = 0; i < 4; ++i) { o[i] = f2bf(v0[i]); o[4 + i] = f2bf(v1[i]); }
  }
  *(u16x8*)(wwsB + (size_t)g * 8) = o;
}

// ---------------- Kernel 1: FUSED, small desynchronized blocks ----------------
// BM=32, 256 thr (4 waves = 4 col-strips x 80; each wave all 32 rows, acc[2][5]).
// 3125 blocks (no row tail). LDS 32 KB (A-tile; phase-2 sOut aliased) -> 4 blocks/CU,
// each at an independent phase (desync). K-loop: ZERO barriers — A from LDS (1-ahead
// ds_read), B from L2-resident wws (1-ahead). Phase 2: B' direct from global wwsB.
#define BN   320
#define RH_LD 328

__global__ __launch_bounds__(256, 4) void k_fused(
    const float* __restrict__ x, const u16* __restrict__ wws, const u16* __restrict__ wwsB,
    const float* __restrict__ fc1b, const float* __restrict__ xencb,
    const int* __restrict__ y, const void* __restrict__ tmask,
    const float* __restrict__ fc2b, const float* __restrict__ pw,
    const int* __restrict__ mask_flag,
    float* __restrict__ out_lp, float* __restrict__ sq_out, float* __restrict__ sk_out)
{
  __shared__ __align__(16) u16 smem[16384];   // 32 KB: sA [32 rows][512 K-pad]
  u16* sOut = smem;                            // phase-2 alias: [32][328] = 21 KB

  const int tid  = threadIdx.x;
  const int lane = tid & 63;
  const int wcol = tid >> 6;                // col strip (0..3)
  const int l15 = lane & 15, lgrp = lane >> 4;
  const long rowbase = (long)blockIdx.x * 32;

  // ---- stage A tile (32 x 512 bf16, zero-padded), XOR-swizzled, 2 load batches ----
  // group g (0..2047): r=g>>6, c=g&63 ; phys = c ^ (r&7) ; src x[rowbase+r][c*8..+8)
  {
    f32x4 v0[4], v1[4];
    #pragma unroll
    for (int half = 0; half < 2; ++half) {
      #pragma unroll
      for (int i = 0; i < 4; ++i) {
        const int g = tid + 256 * (half * 4 + i);
        const int r = g >> 6, c = g & 63;
        const int k0 = c * 8;
        v0[i] = (f32x4){0.f, 0.f, 0.f, 0.f};
        v1[i] = v0[i];
        const float* p = x + (rowbase + r) * F_DIM + k0;
        if (k0 + 4 <= F_DIM) v0[i] = *(const f32x4*)p;
        if (k0 + 8 <= F_DIM) v1[i] = *(const f32x4*)(p + 4);
      }
      #pragma unroll
      for (int i = 0; i < 4; ++i) {
        const int g = tid + 256 * (half * 4 + i);
        const int r = g >> 6, c = g & 63;
        const int phys = c ^ (r & 7);
        u16x8 o;
        #pragma unroll
        for (int j = 0; j < 4; ++j) { o[j] = f2bf(v0[i][j]); o[4 + j] = f2bf(v1[i][j]); }
        *(u16x8*)(smem + r * 512 + phys * 8) = o;
      }
    }
  }

  f32x4 acc[2][5];
  #pragma unroll
  for (int m = 0; m < 2; ++m)
    #pragma unroll
    for (int n = 0; n < 5; ++n)
      acc[m][n] = (f32x4){0.f, 0.f, 0.f, 0.f};

  // B fragment base (validated layout: contiguous 1KB per wave-frag)
  const u16* bbase = wws + (wcol * 80 + l15) * 32 + lgrp * 8;
  // A frag address component: row l15 (m=0) / 16+l15 (m=1), phys group (kc*4+lgrp)^(l15&7)
  const int arow_off = l15 * 512;

#define LB(dst, kc)                                                            \
  {                                                                            \
    const u16* bp = bbase + (size_t)(kc) * (BN * 32);                          \
    _Pragma("unroll")                                                          \
    for (int n = 0; n < 5; ++n) dst[n] = *(const bf16x8*)(bp + n * 512);       \
  }

#define LDA(A0, A1, kc)                                                        \
  {                                                                            \
    const int phys = (((kc) * 4 + lgrp) ^ (l15 & 7)) * 8;                      \
    A0 = *(const bf16x8*)(smem + arow_off + phys);                             \
    A1 = *(const bf16x8*)(smem + arow_off + 16 * 512 + phys);                  \
  }

#define GS(kc, AC0, AC1, AN0, AN1, BU, BL)                                     \
  {                                                                            \
    if ((kc) < 15) { LDA(AN0, AN1, (kc) + 1); LB(BL, (kc) + 1); }              \
    _Pragma("unroll")                                                          \
    for (int n = 0; n < 5; ++n) {                                              \
      acc[0][n] = __builtin_amdgcn_mfma_f32_16x16x32_bf16(AC0, BU[n], acc[0][n], 0, 0, 0); \
      acc[1][n] = __builtin_amdgcn_mfma_f32_16x16x32_bf16(AC1, BU[n], acc[1][n], 0, 0, 0); \
    }                                                                          \
  }

  bf16x8 aX0, aX1, aY0, aY1, bP[5], bQ[5];
  __syncthreads();               // A tile ready (barrier #1)
  LDA(aX0, aX1, 0); LB(bP, 0);

  GS(0,  aX0, aX1, aY0, aY1, bP, bQ)  GS(1,  aY0, aY1, aX0, aX1, bQ, bP)
  GS(2,  aX0, aX1, aY0, aY1, bP, bQ)  GS(3,  aY0, aY1, aX0, aX1, bQ, bP)
  GS(4,  aX0, aX1, aY0, aY1, bP, bQ)  GS(5,  aY0, aY1, aX0, aX1, bQ, bP)
  GS(6,  aX0, aX1, aY0, aY1, bP, bQ)  GS(7,  aY0, aY1, aX0, aX1, bQ, bP)
  GS(8,  aX0, aX1, aY0, aY1, bP, bQ)  GS(9,  aY0, aY1, aX0, aX1, bQ, bP)
  GS(10, aX0, aX1, aY0, aY1, bP, bQ)  GS(11, aY0, aY1, aX0, aX1, bQ, bP)
  GS(12, aX0, aX1, aY0, aY1, bP, bQ)  GS(13, aY0, aY1, aX0, aX1, bQ, bP)
  GS(14, aX0, aX1, aY0, aY1, bP, bQ)  GS(15, aY0, aY1, aX0, aX1, bQ, bP)

  __syncthreads();               // all sA reads done; safe to alias sOut (barrier #2)

  // ---- epilogue: bias+relu -> sOut [32][328] ----
  // C/D: col=l15, row=lgrp*4+rg within frag; m selects row block 0/16.
  #pragma unroll
  for (int n = 0; n < 5; ++n) {
    const int col = wcol * 80 + n * 16 + l15;
    const float bias = (col < H_DIM) ? fc1b[col] : xencb[col - H_DIM];
    #pragma unroll
    for (int m = 0; m < 2; ++m) {
      const int r0 = m * 16 + lgrp * 4;
      #pragma unroll
      for (int rg = 0; rg < 4; ++rg)
        sOut[(r0 + rg) * RH_LD + col] = f2bf(fmaxf(acc[m][n][rg] + bias, 0.f));
    }
  }
  __syncthreads();               // barrier #3

  // ---- rowhead: waves 0-1, 16 rows each; B' frags direct from global (L2) ----
  if (tid < 128) {
    const int wid = tid >> 6;    // 0..1
    const u16* bBase = wwsB + l15 * 32 + lgrp * 8;   // + n*512 + kc*1536
    f32x4 racc[3];
    #pragma unroll
    for (int n = 0; n < 3; ++n) racc[n] = (f32x4){0.f, 0.f, 0.f, 0.f};
    const u16* pa = sOut + (wid * 16 + l15) * RH_LD + lgrp * 8;

    bf16x8 bc[3], bn[3];
    #pragma unroll
    for (int n = 0; n < 3; ++n) bc[n] = *(const bf16x8*)(bBase + n * 512);

#define RH(kc, BC, BN_)                                                        \
    {                                                                          \
      if ((kc) < 9) {                                                          \
        _Pragma("unroll")                                                      \
        for (int n = 0; n < 3; ++n)                                            \
          BN_[n] = *(const bf16x8*)(bBase + ((kc) + 1) * 1536 + n * 512);      \
      }                                                                        \
      const bf16x8 a = *(const bf16x8*)(pa + (kc) * 32);                       \
      _Pragma("unroll")                                                        \
      for (int n = 0; n < 3; ++n)                                              \
        racc[n] = __builtin_amdgcn_mfma_f32_16x16x32_bf16(a, BC[n], racc[n], 0, 0, 0); \
    }

    RH(0, bc, bn) RH(1, bn, bc) RH(2, bc, bn) RH(3, bn, bc) RH(4, bc, bn)
    RH(5, bn, bc) RH(6, bc, bn) RH(7, bn, bc) RH(8, bc, bn) RH(9, bn, bc)
#undef RH

    const int c0 = l15, c1 = 16 + l15, c2 = 32 + l15;
    const bool v2 = (l15 < 8);
    const float b0 = fc2b[c0], b1 = fc2b[c1], b2 = v2 ? fc2b[c2] : 0.f;
    const float wq0 = pw[2 * HX_DIM + c0], wq1 = pw[2 * HX_DIM + c1],
                wq2 = v2 ? pw[2 * HX_DIM + c2] : 0.f;
    const float wk0 = pw[2 * HX_DIM + C_DIM + c0], wk1 = pw[2 * HX_DIM + C_DIM + c1],
                wk2 = v2 ? pw[2 * HX_DIM + C_DIM + c2] : 0.f;
    const bool byte_mask = (*mask_flag != 0);

    #pragma unroll
    for (int rg = 0; rg < 4; ++rg) {
      const long row = rowbase + wid * 16 + lgrp * 4 + rg;
      const float lg0 = racc[0][rg] + b0;
      const float lg1 = racc[1][rg] + b1;
      const float lg2 = racc[2][rg] + b2;
      const float sxq = __shfl(racc[2][rg], (lane & 48) | 8, 64);   // col 40: xe.w_xq
      const float sxk = __shfl(racc[2][rg], (lane & 48) | 9, 64);   // col 41: xe.w_xk

      float m = fmaxf(lg0, lg1);
      if (v2) m = fmaxf(m, lg2);
      #pragma unroll
      for (int off = 1; off < 16; off <<= 1) m = fmaxf(m, __shfl_xor(m, off, 64));
      const float e0 = __expf(lg0 - m), e1 = __expf(lg1 - m),
                  e2 = v2 ? __expf(lg2 - m) : 0.f;
      float s = e0 + e1 + e2;
      #pragma unroll
      for (int off = 1; off < 16; off <<= 1) s += __shfl_xor(s, off, 64);
      const float lse = m + __logf(s);
      const float inv = 1.f / s;

      const int yv = y[row];
      const bool tm = byte_mask ? (((const unsigned char*)tmask)[row] != 0)
                                : (((const int*)tmask)[row] != 0);
      const float p0 = tm ? (c0 == yv ? 1.f : 0.f) : e0 * inv;
      const float p1 = tm ? (c1 == yv ? 1.f : 0.f) : e1 * inv;
      const float p2 = tm ? (c2 == yv ? 1.f : 0.f) : e2 * inv;
      float sq = p0 * wq0 + p1 * wq1 + p2 * wq2;
      float sk = p0 * wk0 + p1 * wk1 + p2 * wk2;
      #pragma unroll
      for (int off = 1; off < 16; off <<= 1) {
        sq += __shfl_xor(sq, off, 64);
        sk += __shfl_xor(sk, off, 64);
      }

      float* lp = out_lp + row * C_DIM;
      lp[c0] = lg0 - lse;
      lp[c1] = lg1 - lse;
      if (v2) lp[c2] = lg2 - lse;
      if (l15 == 0) { sq_out[row] = sq + sxq; sk_out[row] = sk + sxk; }
    }
  }
#undef LB
#undef LDA
#undef GS
}

// ---------------- Kernel 3: edge scores ----------------
__global__ __launch_bounds__(256) void k_edges(
    const int* __restrict__ ei, const int* __restrict__ ein,
    const float* __restrict__ sq, const float* __restrict__ sk,
    const float* __restrict__ pb, float* __restrict__ out)
{
  const int e = blockIdx.x * 256 + threadIdx.x;
  if (e >= E_NUM) return;
  const float b = pb[0];
  const int a0 = ei[e],  a1 = ei[E_NUM + e];
  out[e] = sq[a0] + sk[a1] + b;
  const int c0 = ein[e], c1 = ein[E_NUM + e];
  out[E_NUM + e] = sq[c0] + sk[c1] + b;
}

extern "C" void kernel_launch(void* const* d_in, const int* in_sizes, int n_in,
                              void* d_out, int out_size, void* d_ws, size_t ws_size,
                              hipStream_t stream)
{
  const float* x     = (const float*)d_in[0];
  const int*   y     = (const int*)d_in[1];
  const void*  tm    = d_in[2];
  const int*   ei    = (const int*)d_in[3];
  const int*   ein   = (const int*)d_in[4];
  const float* fc1w  = (const float*)d_in[5];
  const float* fc1b  = (const float*)d_in[6];
  const float* fc2w  = (const float*)d_in[7];
  const float* fc2b  = (const float*)d_in[8];
  const float* xencw = (const float*)d_in[9];
  const float* xencb = (const float*)d_in[10];
  const float* pw    = (const float*)d_in[11];
  const float* pb    = (const float*)d_in[12];
  float* out = (float*)d_out;

  // ws: | s_q | s_k | flag | wws (320 KB) | wwsB (30 KB)
  float* sq   = (float*)((char*)d_ws + (size_t)N_NODES * O_DIM * 2);
  float* sk   = sq + N_NODES;
  int*   flag = (int*)(sk + N_NODES);
  u16*   wws  = (u16*)((char*)d_ws + 64800064);
  u16*   wwsB = (u16*)((char*)d_ws + 65127744);

  k_detect<<<1, 256, 0, stream>>>((const u32*)tm, flag);
  k_cvtw  <<<80, 256, 0, stream>>>(fc1w, xencw, wws);
  k_cvtw2 <<<8, 256, 0, stream>>>(fc2w, pw, wwsB);
  k_fused <<<N_NODES / 32, 256, 0, stream>>>(x, wws, wwsB, fc1b, xencb, y, tm,
                                             fc2b, pw, flag,
                                             out + 2 * (size_t)E_NUM, sq, sk);
  k_edges <<<E_NUM / 256, 256, 0, stream>>>(ei, ein, sq, sk, pb, out);
}